// Round 8
// baseline (257.019 us; speedup 1.0000x reference)
//
#include <hip/hip_runtime.h>
#include <hip/hip_bf16.h>

// B=2, T=2048, DM=1024, H=16, DK=DV=64
// ws layout (56 MB):
//   [0,2)MB  Wqt bf16 [n=h*64+k][d]   [2,4) Wkt   [4,6) Wvt   [6,8) Wot [n=DM][k=H*DV]
//   [8,32)   Xb bf16 [3][4096][1024]  (xq,xk,xv cast)  -- dead after proj
//   [8,16)   AO bf16 [t][h*64+dv]     (ALIASES Xq slot; written by attn)
//   [32,40)  Qb bf16 [b][h][t][dk]
//   [40,48)  Kt2 bf16 [bh][64 ktile][s:1][dc:1][c:16][q4:4][j:8]  (K A-frag tiled)
//   [48,56)  Vt2 bf16 [bh][64 ktile][64 dv][32 k']  (V^T tiled, key-permuted sigma)

typedef __attribute__((ext_vector_type(8))) short short8;
typedef __attribute__((ext_vector_type(4))) short short4v;
typedef __attribute__((ext_vector_type(4))) float f32x4;
typedef __attribute__((ext_vector_type(4))) int i32x4;

__device__ __forceinline__ short f2bf(float f) {
  union { float f; unsigned u; } v; v.f = f;
  unsigned r = v.u + 0x7FFFu + ((v.u >> 16) & 1u);  // RNE
  return (short)(r >> 16);
}

#define GLD_LDS(g, l) __builtin_amdgcn_global_load_lds( \
    (const __attribute__((address_space(1))) void*)(g), \
    (__attribute__((address_space(3))) void*)(l), 16, 0, 0)

// ---------------- fused prep: x cast | Wq/k/v transpose | Wo transpose -----
__global__ __launch_bounds__(256) void prep_all(
    const float* __restrict__ xq, const float* __restrict__ xk,
    const float* __restrict__ xv, const float* __restrict__ wq,
    const float* __restrict__ wk, const float* __restrict__ wv,
    const float* __restrict__ wo,
    short* __restrict__ Xb, short* __restrict__ Wall, short* __restrict__ Wot)
{
  const int bx = blockIdx.x, tid = threadIdx.x;
  __shared__ float Lt[64][65];
  if (bx < 6144) {                       // ---- x cast (2048 blocks per z)
    int z = bx >> 11;
    const float* x = z == 0 ? xq : (z == 1 ? xk : xv);
    size_t i = ((size_t)(bx & 2047) * 256 + tid) * 8;
    f32x4 f0 = *(const f32x4*)(x + i);
    f32x4 f1 = *(const f32x4*)(x + i + 4);
    short8 s;
#pragma unroll
    for (int j = 0; j < 4; j++) { s[j] = f2bf(f0[j]); s[4 + j] = f2bf(f1[j]); }
    *(short8*)(Xb + (size_t)z * 4194304 + i) = s;
  } else if (bx < 6912) {                // ---- Wq/k/v transpose (256 per z)
    int bz = bx - 6144;
    int z = bz >> 8, inner = bz & 255;
    const float* w = z == 0 ? wq : (z == 1 ? wk : wv);
    short* Wt = Wall + (size_t)z * 1048576;
    int h = inner >> 4, d0 = (inner & 15) * 64;
#pragma unroll
    for (int it = 0; it < 4; it++) {
      int e = tid + it * 256;
      int dl = e >> 4, k4 = (e & 15) * 4;
      f32x4 v = *(const f32x4*)(w + ((size_t)(h * 1024 + d0 + dl) * 64) + k4);
#pragma unroll
      for (int j = 0; j < 4; j++) Lt[dl][k4 + j] = v[j];
    }
    __syncthreads();
#pragma unroll
    for (int it = 0; it < 4; it++) {
      int e = tid + it * 256;
      int kl = e >> 4, dq = e & 15;
      short4v s;
#pragma unroll
      for (int j = 0; j < 4; j++) s[j] = f2bf(Lt[dq * 4 + j][kl]);
      *(short4v*)(Wt + (size_t)(h * 64 + kl) * 1024 + d0 + dq * 4) = s;
    }
  } else {                               // ---- Wo transpose (256 blocks)
    int bz = bx - 6912;
    int k0 = (bz >> 4) * 64, n0 = (bz & 15) * 64;
#pragma unroll
    for (int it = 0; it < 4; it++) {
      int e = tid + it * 256;
      int kl = e >> 4, n4 = (e & 15) * 4;
      f32x4 v = *(const f32x4*)(wo + (size_t)(k0 + kl) * 1024 + n0 + n4);
#pragma unroll
      for (int j = 0; j < 4; j++) Lt[kl][n4 + j] = v[j];
    }
    __syncthreads();
#pragma unroll
    for (int it = 0; it < 4; it++) {
      int e = tid + it * 256;
      int nl = e >> 4, kq = e & 15;
      short4v s;
#pragma unroll
      for (int j = 0; j < 4; j++) s[j] = f2bf(Lt[kq * 4 + j][nl]);
      *(short4v*)(Wot + (size_t)(n0 + nl) * 1024 + k0 + kq * 4) = s;
    }
  }
}

// ---------------- QKV projection: m97-style 128x128 LDS-staged GEMM --------
// z==1 (K) writes A-frag-tiled Kt2 (vectorized short4 stores).
// z==2 (V) computes with SWAPPED MFMA operands (D transposed) so the
//          key-permuted Vt2 store is contiguous short4 per lane.
__global__ __launch_bounds__(256) void proj_qkv2(
    const short* __restrict__ Xb, const short* __restrict__ Wall,
    short* __restrict__ Qb, short* __restrict__ Kt2, short* __restrict__ Vt2)
{
  const int z = blockIdx.z;
  const short* X  = Xb   + (size_t)z * 4194304;
  const short* Wt = Wall + (size_t)z * 1048576;

  const int t0 = blockIdx.x * 128;   // 32
  const int n0 = blockIdx.y * 128;   // 8
  const int tid = threadIdx.x, w = tid >> 6, lane = tid & 63;
  const int c = lane & 15, q4 = lane >> 4;
  const int wn = (w & 1) * 64, wt = (w >> 1) * 64;
  const int srow = lane >> 2, scol = (lane & 3) * 8;

  __shared__ __align__(16) short Al[128 * 32];
  __shared__ __align__(16) short Bl[128 * 32];

  f32x4 acc[4][4] = {};

  for (int k0 = 0; k0 < 1024; k0 += 32) {
#pragma unroll
    for (int i = 0; i < 2; i++) {
      int rg = (w * 2 + i) * 16;
      GLD_LDS(Wt + (size_t)(n0 + rg + srow) * 1024 + k0 + scol, Al + rg * 32);
      GLD_LDS(X  + (size_t)(t0 + rg + srow) * 1024 + k0 + scol, Bl + rg * 32);
    }
    __syncthreads();
    short8 a[4], bfr[4];
#pragma unroll
    for (int i = 0; i < 4; i++)
      a[i] = *(const short8*)(Al + (wn + i * 16 + c) * 32 + q4 * 8);
#pragma unroll
    for (int j = 0; j < 4; j++)
      bfr[j] = *(const short8*)(Bl + (wt + j * 16 + c) * 32 + q4 * 8);
    if (z == 2) {
      // swapped: D[m=t][n=dv] -> lane col = dv, regs = 4 consecutive t
#pragma unroll
      for (int i = 0; i < 4; i++)
#pragma unroll
        for (int j = 0; j < 4; j++)
          acc[i][j] = __builtin_amdgcn_mfma_f32_16x16x32_bf16(bfr[j], a[i], acc[i][j], 0, 0, 0);
    } else {
#pragma unroll
      for (int i = 0; i < 4; i++)
#pragma unroll
        for (int j = 0; j < 4; j++)
          acc[i][j] = __builtin_amdgcn_mfma_f32_16x16x32_bf16(a[i], bfr[j], acc[i][j], 0, 0, 0);
    }
    __syncthreads();
  }

#pragma unroll
  for (int i = 0; i < 4; i++)
#pragma unroll
    for (int j = 0; j < 4; j++) {
      f32x4 v = acc[i][j];
      short4v pk;
#pragma unroll
      for (int r = 0; r < 4; r++) pk[r] = f2bf(v[r]);
      if (z == 0) {
        int n = n0 + wn + i * 16 + q4 * 4;       // h*64 + dk base
        int trow = t0 + wt + j * 16 + c;
        int b = trow >> 11, t = trow & 2047;
        int h = n >> 6, cc = n & 63;
        *(short4v*)(Qb + (size_t)((b * 16 + h) * 2048 + t) * 64 + cc) = pk;
      } else if (z == 1) {
        int n = n0 + wn + i * 16 + q4 * 4;       // h*64 + dk base, cc..cc+3
        int trow = t0 + wt + j * 16 + c;
        int b = trow >> 11, t = trow & 2047;
        int h = n >> 6, cc = n & 63;
        int t5 = t & 31, s_ = t5 >> 4, c_ = t5 & 15;
        size_t base = (size_t)(b * 16 + h) * 131072 + (t >> 5) * 2048;
        // frag layout: ((s*2+dc)*16 + key)*32 + q4'*8 + j ; cc..cc+3 contiguous
        *(short4v*)(Kt2 + base + ((s_ * 2 + (cc >> 5)) * 16 + c_) * 32
                        + ((cc >> 3) & 3) * 8 + (cc & 7)) = pk;
      } else {
        // transposed D: lane col = dv, regs = t..t+3
        int dv = n0 + wn + i * 16 + c;
        int trow = t0 + wt + j * 16 + q4 * 4;    // 4 consecutive t in regs
        int b = trow >> 11, t = trow & 2047;
        int h = dv >> 6, cc = dv & 63;
        int t5 = t & 31;                          // %4 == 0
        int kp = ((t5 >> 2) & 3) * 8 + ((t5 >> 4) & 1) * 4;  // sigma base, +r contiguous
        size_t base = (size_t)(b * 16 + h) * 131072 + (t >> 5) * 2048;
        *(short4v*)(Vt2 + base + (size_t)cc * 32 + kp) = pk;
      }
    }
}

// ---------------- fused attention v6: 1-wave blocks, 64 q-rows/wave --------
// Grid (32, 32), block 64. Wave owns 64 q-rows (4 panels of 16) -> halves
// per-wave K/V L2 traffic vs v5 and doubles ILP across u-panels.
// K double-buffered (prefetch distance 1), V single-buffered (top-of-body
// load, end-of-body use ~250cyc later > L2 latency). No LDS, no barriers.
__global__ __launch_bounds__(64, 2) void attn6(
    const short* __restrict__ Qb, const short* __restrict__ Kt2,
    const short* __restrict__ Vt2, const float* __restrict__ mask,
    short* __restrict__ AO)
{
  const int tblk = blockIdx.x;   // 32 tiles of 64 q-rows
  const int bh = blockIdx.y;
  const int b = bh >> 4, h = bh & 15;
  const short* Qh = Qb  + (size_t)bh * 131072;
  const short* Kh = Kt2 + (size_t)bh * 131072;
  const short* Vh = Vt2 + (size_t)bh * 131072;

  const int lane = threadIdx.x & 63;
  const int c = lane & 15, q4 = lane >> 4;
  const int qrow0 = tblk * 64;

  // Q fragments (B-operand: n=qrow=c, k=q4*8+j), 4 panels
  short8 qa[4][2];
#pragma unroll
  for (int u = 0; u < 4; u++)
#pragma unroll
    for (int dc = 0; dc < 2; dc++)
      qa[u][dc] = *(const short8*)(Qh + (size_t)(qrow0 + u * 16 + c) * 64 + dc * 32 + q4 * 8);

  f32x4 acc[4][4] = {};
  float l[4] = {0.f, 0.f, 0.f, 0.f};
  const float LOG2E_64 = 1.44269504088896f * 0.015625f;

  const short* kP = Kh + c * 32 + q4 * 8;   // frag (s,dc) at +(s*2+dc)*512
  const short* vP = Vh + c * 32 + q4 * 8;   // frag (vs)  at +vs*512
  const float* mP = mask + b * 2048 + q4 * 4;

  short8 kf0[4], kf1[4], va[4];

#define PREF_K(KF) do { \
    KF[0] = *(const short8*)(kP);        KF[1] = *(const short8*)(kP + 512); \
    KF[2] = *(const short8*)(kP + 1024); KF[3] = *(const short8*)(kP + 1536); \
    kP += 2048; \
  } while (0)

#define BODY(KF, KFN, doPref) do { \
    va[0] = *(const short8*)(vP);        va[1] = *(const short8*)(vP + 512); \
    va[2] = *(const short8*)(vP + 1024); va[3] = *(const short8*)(vP + 1536); \
    vP += 2048; \
    f32x4 st[4][2]; \
    _Pragma("unroll") \
    for (int u = 0; u < 4; u++) \
      _Pragma("unroll") \
      for (int s = 0; s < 2; s++) { \
        f32x4 z0 = {}; \
        z0 = __builtin_amdgcn_mfma_f32_16x16x32_bf16(KF[s * 2], qa[u][0], z0, 0, 0, 0); \
        st[u][s] = __builtin_amdgcn_mfma_f32_16x16x32_bf16(KF[s * 2 + 1], qa[u][1], z0, 0, 0, 0); \
      } \
    if (doPref) PREF_K(KFN); \
    f32x4 cm[2], cb[2]; \
    _Pragma("unroll") \
    for (int s = 0; s < 2; s++) { \
      f32x4 mk = *(const f32x4*)(mP + s * 16); \
      cm[s] = mk * LOG2E_64; \
      cb[s] = (mk - 1.0f) * 240.0f; \
    } \
    mP += 32; \
    _Pragma("unroll") \
    for (int u = 0; u < 4; u++) { \
      unsigned pkd[2][2]; \
      _Pragma("unroll") \
      for (int s = 0; s < 2; s++) { \
        float e0 = __builtin_amdgcn_exp2f(st[u][s][0] * cm[s][0] + cb[s][0]); \
        float e1 = __builtin_amdgcn_exp2f(st[u][s][1] * cm[s][1] + cb[s][1]); \
        float e2 = __builtin_amdgcn_exp2f(st[u][s][2] * cm[s][2] + cb[s][2]); \
        float e3 = __builtin_amdgcn_exp2f(st[u][s][3] * cm[s][3] + cb[s][3]); \
        l[u] += (e0 + e1) + (e2 + e3); \
        union { float f; unsigned u; } a0, a1, a2, a3; \
        a0.f = e0; a1.f = e1; a2.f = e2; a3.f = e3; \
        pkd[s][0] = __builtin_amdgcn_perm(a1.u + 0x8000u, a0.u + 0x8000u, 0x07060302u); \
        pkd[s][1] = __builtin_amdgcn_perm(a3.u + 0x8000u, a2.u + 0x8000u, 0x07060302u); \
      } \
      union { i32x4 i; short8 s; } pb; \
      pb.i[0] = (int)pkd[0][0]; pb.i[1] = (int)pkd[0][1]; \
      pb.i[2] = (int)pkd[1][0]; pb.i[3] = (int)pkd[1][1]; \
      _Pragma("unroll") \
      for (int vs = 0; vs < 4; vs++) \
        acc[u][vs] = __builtin_amdgcn_mfma_f32_16x16x32_bf16(va[vs], pb.s, acc[u][vs], 0, 0, 0); \
    } \
  } while (0)

  PREF_K(kf0);                    // tile 0
  for (int ii = 0; ii < 32; ii++) {
    BODY(kf0, kf1, 1);            // body 2ii,   prefetch 2ii+1
    BODY(kf1, kf0, ii < 31);      // body 2ii+1, prefetch 2ii+2
  }
#undef PREF_K
#undef BODY

  // epilogue: l reduce across q4 groups, normalize, store
#pragma unroll
  for (int u = 0; u < 4; u++) {
    float lu = l[u];
    lu += __shfl_xor(lu, 16);
    lu += __shfl_xor(lu, 32);
    float inv = 1.0f / lu;
    size_t row = (size_t)b * 2048 + qrow0 + u * 16 + c;
#pragma unroll
    for (int vs = 0; vs < 4; vs++) {
      f32x4 v = acc[u][vs];
      short4v pk;
#pragma unroll
      for (int r = 0; r < 4; r++) pk[r] = f2bf(v[r] * inv);
      *(short4v*)(AO + row * 1024 + h * 64 + vs * 16 + q4 * 4) = pk;
    }
  }
}

// ---------------- output projection: m97 GEMM, fp32+bias epilogue ----------
__global__ __launch_bounds__(256) void out_proj2(
    const short* __restrict__ AO, const short* __restrict__ Wot,
    const float* __restrict__ bo, float* __restrict__ out)
{
  const int t0 = blockIdx.x * 128;   // 32
  const int n0 = blockIdx.y * 128;   // 8
  const int tid = threadIdx.x, w = tid >> 6, lane = tid & 63;
  const int c = lane & 15, q4 = lane >> 4;
  const int wn = (w & 1) * 64, wt = (w >> 1) * 64;
  const int srow = lane >> 2, scol = (lane & 3) * 8;

  __shared__ __align__(16) short Al[128 * 32];
  __shared__ __align__(16) short Bl[128 * 32];

  f32x4 acc[4][4] = {};

  for (int k0 = 0; k0 < 1024; k0 += 32) {
#pragma unroll
    for (int i = 0; i < 2; i++) {
      int rg = (w * 2 + i) * 16;
      GLD_LDS(Wot + (size_t)(n0 + rg + srow) * 1024 + k0 + scol, Al + rg * 32);
      GLD_LDS(AO  + (size_t)(t0 + rg + srow) * 1024 + k0 + scol, Bl + rg * 32);
    }
    __syncthreads();
    short8 a[4], bfr[4];
#pragma unroll
    for (int i = 0; i < 4; i++)
      a[i] = *(const short8*)(Al + (wn + i * 16 + c) * 32 + q4 * 8);
#pragma unroll
    for (int j = 0; j < 4; j++)
      bfr[j] = *(const short8*)(Bl + (wt + j * 16 + c) * 32 + q4 * 8);
#pragma unroll
    for (int i = 0; i < 4; i++)
#pragma unroll
      for (int j = 0; j < 4; j++)
        acc[i][j] = __builtin_amdgcn_mfma_f32_16x16x32_bf16(a[i], bfr[j], acc[i][j], 0, 0, 0);
    __syncthreads();
  }

#pragma unroll
  for (int i = 0; i < 4; i++)
#pragma unroll
    for (int j = 0; j < 4; j++) {
      int n = n0 + wn + i * 16 + q4 * 4;
      int trow = t0 + wt + j * 16 + c;
      f32x4 v = acc[i][j] + *(const f32x4*)(bo + n);
      *(f32x4*)(out + (size_t)trow * 1024 + n) = v;
    }
}

extern "C" void kernel_launch(void* const* d_in, const int* in_sizes, int n_in,
                              void* d_out, int out_size, void* d_ws, size_t ws_size,
                              hipStream_t stream)
{
  (void)in_sizes; (void)n_in; (void)out_size; (void)ws_size;
  const float* xq   = (const float*)d_in[0];
  const float* xk   = (const float*)d_in[1];
  const float* xv   = (const float*)d_in[2];
  const float* mask = (const float*)d_in[3];
  const float* wq   = (const float*)d_in[4];
  const float* wk   = (const float*)d_in[5];
  const float* wv   = (const float*)d_in[6];
  const float* wo   = (const float*)d_in[7];
  const float* bo   = (const float*)d_in[8];
  float* out = (float*)d_out;

  char* ws = (char*)d_ws;                    // needs 56 MB
  short* Wall = (short*)(ws + (size_t)0);    // Wq/Wk/Wv contiguous
  short* Wot  = (short*)(ws + ((size_t)6 << 20));
  short* Xb   = (short*)(ws + ((size_t)8 << 20));   // 24 MB, dead after proj
  short* AO   = (short*)(ws + ((size_t)8 << 20));   // aliases Xq slot (8 MB)
  short* Qb   = (short*)(ws + ((size_t)32 << 20));
  short* Kt2  = (short*)(ws + ((size_t)40 << 20));  // K A-frag pre-tiled
  short* Vt2  = (short*)(ws + ((size_t)48 << 20));  // V^T pre-tiled, key-permuted

  prep_all<<<7168, 256, 0, stream>>>(xq, xk, xv, wq, wk, wv, wo, Xb, Wall, Wot);
  proj_qkv2<<<dim3(32, 8, 3), 256, 0, stream>>>(Xb, Wall, Qb, Kt2, Vt2);
  attn6<<<dim3(32, 32), 64, 0, stream>>>(Qb, Kt2, Vt2, mask, AO);
  out_proj2<<<dim3(32, 8), 256, 0, stream>>>(AO, Wot, bo, out);
}